// Round 2
// baseline (110.360 us; speedup 1.0000x reference)
//
#include <hip/hip_runtime.h>

typedef _Float16 h8 __attribute__((ext_vector_type(8)));
typedef _Float16 h4 __attribute__((ext_vector_type(4)));
typedef float f4 __attribute__((ext_vector_type(4)));
typedef unsigned int uint32;

#define NT 7   // n-tiles: 112 output cols (100 + pad)
#define KC 4   // k-chunks of 32: 128 (100 + pad)

__global__ __launch_bounds__(256, 2)
void grnn_fused(const float* __restrict__ times,
                const float* __restrict__ Qw,
                const float* __restrict__ Qb,
                const float* __restrict__ Ww,
                const float* __restrict__ Wb,
                const float* __restrict__ Pw,
                const float* __restrict__ Pb,
                float* __restrict__ out)
{
  // Hs stride 132 halves: even-row b64 A-reads are 2-way (free) bank-wise;
  // 8B alignment holds for every row (264 % 8 == 0).
  __shared__ __align__(16) _Float16 Hs[256][132];   // 67584 B (also Ww fp32 staging: 40000 B)
  __shared__ __align__(16) float t_s[1024];         // 4096 B
  __shared__ __align__(16) float qw_s[128];
  __shared__ __align__(16) float qb_s[128];
  __shared__ __align__(16) float qbw_s[128];        // Qb + Wb

  const int tid  = threadIdx.x;
  const int wave = tid >> 6;
  const int lane = tid & 63;
  const int l15  = lane & 15;
  const int kg   = lane >> 4;
  const int tree = blockIdx.x;

  // ---- phase 0: stage times, Q vectors, and raw Ww (fp32) into Hs ----
  {
    const float* tg = times + tree * 1023;
    for (int i = tid; i < 1023; i += 256) t_s[i] = tg[i];
    if (tid < 128) {
      float qw = 0.f, qb = 0.f, wb = 0.f;
      if (tid < 100) { qw = Qw[tid]; qb = Qb[tid]; wb = Wb[tid]; }
      qw_s[tid] = qw; qb_s[tid] = qb; qbw_s[tid] = qb + wb;
    }
    f4* wsv = (f4*)&Hs[0][0];
    const f4* wg = (const f4*)Ww;            // 10000 floats = 2500 float4
    for (int i = tid; i < 2500; i += 256) wsv[i] = wg[i];
  }
  __syncthreads();

  // ---- phase 1: build persistent W fragments (B[k][n] = Ww[n][k]) ----
  h8 wf[NT][KC];
  {
    const float* wsf = (const float*)&Hs[0][0];
    #pragma unroll
    for (int nt = 0; nt < NT; ++nt) {
      const int r = nt * 16 + l15;           // output feature (Ww row)
      #pragma unroll
      for (int kc = 0; kc < KC; ++kc) {
        const int kb = kc * 32 + kg * 8;     // k base for this lane group
        h8 v;
        #pragma unroll
        for (int j = 0; j < 8; ++j) v[j] = (_Float16)0.f;
        if (r < 100 && kb < 100) {
          const int lim = 100 - kb;          // 4 (kb==96) or >=8
          const int base = r * 100 + kb;
          #pragma unroll
          for (int j = 0; j < 8; ++j)
            if (j < lim) v[j] = (_Float16)wsf[base + j];
        }
        wf[nt][kc] = v;
      }
    }
  }
  __syncthreads();

  // MFMA + epilogue for one m-tile: D[m][n] row=(lane>>4)*4+reg, col=lane&15
  auto do_mt = [&](int mt, const h8* afr, int s) {
    #pragma unroll
    for (int nt = 0; nt < NT; ++nt) {
      f4 acc = {0.f, 0.f, 0.f, 0.f};
      #pragma unroll
      for (int kc = 0; kc < KC; ++kc)
        acc = __builtin_amdgcn_mfma_f32_16x16x32_f16(afr[kc], wf[nt][kc], acc, 0, 0, 0);
      const int o = nt * 16 + l15;
      if (o < 100) {
        const float qw = qw_s[o];
        const float qbw = qbw_s[o];
        const int mr = mt * 16 + kg * 4;
        #pragma unroll
        for (int r = 0; r < 4; ++r) {
          float tv = t_s[s + mr + r];
          float v = acc[r] + tv * qw + qbw;
          Hs[mr + r][o] = (_Float16)fmaxf(v, 0.f);
        }
      }
    }
  };

  // A fragment = comb[m][k] = Hs[2m][k] + Hs[2m+1][k], A[m=lane&15][k=kg*8+j]
  auto load_afr = [&](int mt, h8* afr) {
    const int m2 = (mt * 16 + l15) * 2;
    #pragma unroll
    for (int kc = 0; kc < KC; ++kc) {
      const int kb = kc * 32 + kg * 8;
      h4 a0 = *(const h4*)&Hs[m2][kb];
      h4 b0 = *(const h4*)&Hs[m2][kb + 4];
      h4 a1 = *(const h4*)&Hs[m2 + 1][kb];
      h4 b1 = *(const h4*)&Hs[m2 + 1][kb + 4];
      h4 lo = a0 + a1, hi = b0 + b1;
      afr[kc] = __builtin_shufflevector(lo, hi, 0, 1, 2, 3, 4, 5, 6, 7);
    }
  };

  // ---- phase 2: zero pad cols 100..131 + level 8 with fused leaves ----
  {
    uint32* hw = (uint32*)&Hs[0][0];
    for (int i = tid; i < 256 * 16; i += 256) {
      const int row = i >> 4;
      hw[row * 66 + 50 + (i & 15)] = 0u;   // halves 100..131 of each row
    }
  }
  {
    #pragma unroll
    for (int i = 0; i < 4; ++i) {
      const int mt = wave + 4 * i;         // 16 m-tiles over 4 waves
      const int m = mt * 16 + l15;
      const float t0 = t_s[511 + 2 * m];   // leaf children of level-8 node m
      const float t1 = t_s[512 + 2 * m];
      h8 afr[KC];
      #pragma unroll
      for (int kc = 0; kc < KC; ++kc) {
        const int kb = kc * 32 + kg * 8;
        const f4 qwa = *(const f4*)&qw_s[kb];
        const f4 qwb = *(const f4*)&qw_s[kb + 4];
        const f4 qba = *(const f4*)&qb_s[kb];
        const f4 qbb = *(const f4*)&qb_s[kb + 4];
        #pragma unroll
        for (int j = 0; j < 4; ++j) {
          float h0 = fmaxf(t0 * qwa[j] + qba[j], 0.f);
          float h1 = fmaxf(t1 * qwa[j] + qba[j], 0.f);
          afr[kc][j] = (_Float16)(h0 + h1);          // pads auto-zero (qw=qb=0)
          float g0 = fmaxf(t0 * qwb[j] + qbb[j], 0.f);
          float g1 = fmaxf(t1 * qwb[j] + qbb[j], 0.f);
          afr[kc][j + 4] = (_Float16)(g0 + g1);
        }
      }
      do_mt(mt, afr, 255);
    }
  }
  __syncthreads();

  // ---- level 7: 8 m-tiles, 2 per wave; preload-then-barrier for WAR ----
  {
    h8 a0[KC], a1[KC];
    load_afr(wave, a0);
    load_afr(wave + 4, a1);
    __syncthreads();
    do_mt(wave, a0, 127);
    do_mt(wave + 4, a1, 127);
  }
  __syncthreads();
  // ---- level 6: 4 m-tiles ----
  {
    h8 a0[KC];
    load_afr(wave, a0);
    __syncthreads();
    do_mt(wave, a0, 63);
  }
  __syncthreads();
  // ---- level 5: 2 m-tiles ----
  {
    h8 a0[KC];
    if (wave < 2) load_afr(wave, a0);
    __syncthreads();
    if (wave < 2) do_mt(wave, a0, 31);
  }
  __syncthreads();
  // ---- levels 4..0: single m-tile, wave 0 only (in-wave program order
  // makes reads-before-writes safe; no barriers needed) ----
  if (wave == 0) {
    for (int d = 4; d >= 0; --d) {
      h8 a0[KC];
      load_afr(0, a0);
      do_mt(0, a0, (1 << d) - 1);
    }
  }
  __syncthreads();

  // ---- projection: out[p] = root . Pw[p] + Pb[p], p<5 ----
  if (tid < 160) {
    const int p = tid >> 5;
    const int j = tid & 31;
    float sum = 0.f;
    #pragma unroll
    for (int c = 0; c < 4; ++c) {
      const int o = j + 32 * c;
      if (o < 100) sum += (float)Hs[0][o] * Pw[p * 100 + o];
    }
    sum += __shfl_down(sum, 16, 32);
    sum += __shfl_down(sum, 8, 32);
    sum += __shfl_down(sum, 4, 32);
    sum += __shfl_down(sum, 2, 32);
    sum += __shfl_down(sum, 1, 32);
    if (j == 0) out[tree * 5 + p] = sum + Pb[p];
  }
}

extern "C" void kernel_launch(void* const* d_in, const int* in_sizes, int n_in,
                              void* d_out, int out_size, void* d_ws, size_t ws_size,
                              hipStream_t stream) {
  (void)n_in; (void)out_size; (void)d_ws; (void)ws_size;
  const float* times = (const float*)d_in[0];
  const float* Qw = (const float*)d_in[1];
  const float* Qb = (const float*)d_in[2];
  const float* Ww = (const float*)d_in[3];
  const float* Wb = (const float*)d_in[4];
  const float* Pw = (const float*)d_in[5];
  const float* Pb = (const float*)d_in[6];
  float* outp = (float*)d_out;
  const int B = in_sizes[0] / 1023;   // 1024 trees
  grnn_fused<<<dim3(B), dim3(256), 0, stream>>>(times, Qw, Qb, Ww, Wb, Pw, Pb, outp);
}